// Round 1
// baseline (838.114 us; speedup 1.0000x reference)
//
#include <hip/hip_runtime.h>
#include <math.h>

// ---------------- helpers ----------------
__device__ __forceinline__ float lanebcast(float v, int l) {
  return __int_as_float(__builtin_amdgcn_readlane(__float_as_int(v), l));
}

__device__ __forceinline__ float wave_sum(float v) {
#pragma unroll
  for (int off = 32; off > 0; off >>= 1) v += __shfl_xor(v, off, 64);
  return v;
}

// ---------------- CSR build ----------------
__global__ void k_initdeg(int* deg, int n) {
  int i = blockIdx.x * blockDim.x + threadIdx.x;
  if (i < n) deg[i] = 1;  // self-loop
}

__global__ void k_count(const int* __restrict__ dst, int* deg, int E) {
  int e = blockIdx.x * blockDim.x + threadIdx.x;
  if (e < E) atomicAdd(&deg[dst[e]], 1);
}

// single-block exclusive scan (N up to ~8M)
__global__ void k_scan(const int* __restrict__ deg, int* rowstart, int* cursor, int n) {
  __shared__ int smem[1024];
  __shared__ int carry_s;
  int tid = threadIdx.x;
  if (tid == 0) carry_s = 0;
  __syncthreads();
  const int PER = 8;
  for (int base = 0; base < n; base += 1024 * PER) {
    int vals[PER];
    int s = 0;
#pragma unroll
    for (int p = 0; p < PER; p++) {
      int i = base + tid * PER + p;
      int v = (i < n) ? deg[i] : 0;
      vals[p] = v;
      s += v;
    }
    smem[tid] = s;
    __syncthreads();
    for (int off = 1; off < 1024; off <<= 1) {
      int t = (tid >= off) ? smem[tid - off] : 0;
      __syncthreads();
      smem[tid] += t;
      __syncthreads();
    }
    int c = carry_s;
    int excl = smem[tid] - s + c;
    __syncthreads();
    if (tid == 1023) carry_s = c + smem[1023];
#pragma unroll
    for (int p = 0; p < PER; p++) {
      int i = base + tid * PER + p;
      if (i < n) { rowstart[i] = excl; cursor[i] = excl; }
      excl += vals[p];
    }
    __syncthreads();
  }
  if (tid == 0) rowstart[n] = carry_s;
}

__global__ void k_dinv(const int* __restrict__ deg, float* dinv, int n) {
  int i = blockIdx.x * blockDim.x + threadIdx.x;
  if (i < n) dinv[i] = 1.0f / sqrtf((float)deg[i]);
}

__global__ void k_scatter(const int* __restrict__ ei_src, const int* __restrict__ ei_dst,
                          int* cursor, int* colidx, int E, int n) {
  int e = blockIdx.x * blockDim.x + threadIdx.x;
  if (e >= E + n) return;
  int s, d;
  if (e < E) { s = ei_src[e]; d = ei_dst[e]; }
  else       { s = e - E; d = s; }
  int pos = atomicAdd(&cursor[d], 1);
  colidx[pos] = s;
}

// ---------------- GEMM: H[N,MJ*64] = A[N,K] @ W[K,MJ*64] ----------------
// wave-per-4-rows, lane = output column (mod 64). W staged in LDS, relaid so
// lane reads MJ contiguous floats (ds_read_b128 for MJ=4). Row values are
// broadcast from lane registers via v_readlane. FUSE adds the GAT attention
// einsum on the in-register accumulators.
template <int K, int MJ, bool FUSE>
__global__ __launch_bounds__(256) void k_gemm(
    const float* __restrict__ A, const float* __restrict__ W,
    float* __restrict__ H, int n,
    const float* __restrict__ att_src, const float* __restrict__ att_dst,
    float* __restrict__ a_src, float* __restrict__ a_dst) {
  __shared__ __align__(16) float lds_w[K * MJ * 64];
  int tid = threadIdx.x;
  for (int idx = tid; idx < K * MJ * 64; idx += 256) {
    int k = idx / (MJ * 64), cp = idx % (MJ * 64);
    int j = cp / 64, l = cp % 64;
    lds_w[k * MJ * 64 + l * MJ + j] = W[idx];
  }
  __syncthreads();
  int wave = tid >> 6, lane = tid & 63;

  float atts[MJ], attd[MJ];
  if constexpr (FUSE) {
#pragma unroll
    for (int j = 0; j < MJ; j++) {
      atts[j] = att_src[j * 64 + lane];
      attd[j] = att_dst[j * 64 + lane];
    }
  }

  const int ROWS = 4;
  const int XR = (K + 63) / 64;
  for (int rowbase = (blockIdx.x * 4 + wave) * ROWS; rowbase < n;
       rowbase += gridDim.x * 4 * ROWS) {
    float xr[ROWS][XR];
#pragma unroll
    for (int r = 0; r < ROWS; r++) {
      int row = rowbase + r;
#pragma unroll
      for (int q = 0; q < XR; q++)
        xr[r][q] = (row < n) ? A[(size_t)row * K + q * 64 + lane] : 0.0f;
    }
    float acc[ROWS][MJ];
#pragma unroll
    for (int r = 0; r < ROWS; r++)
#pragma unroll
      for (int j = 0; j < MJ; j++) acc[r][j] = 0.0f;

#pragma unroll
    for (int q = 0; q < XR; q++) {
#pragma unroll 8
      for (int kk = 0; kk < 64; kk++) {
        int k = q * 64 + kk;
        float wv[MJ];
        if constexpr (MJ == 4) {
          const float4 t = *(const float4*)&lds_w[(k * 64 + lane) * 4];
          wv[0] = t.x; wv[1] = t.y; wv[2] = t.z; wv[3] = t.w;
        } else {
          wv[0] = lds_w[k * 64 + lane];
        }
#pragma unroll
        for (int r = 0; r < ROWS; r++) {
          float xv = lanebcast(xr[r][q], kk);
#pragma unroll
          for (int j = 0; j < MJ; j++) acc[r][j] = fmaf(xv, wv[j], acc[r][j]);
        }
      }
    }

#pragma unroll
    for (int r = 0; r < ROWS; r++) {
      int row = rowbase + r;
      if (row < n) {
#pragma unroll
        for (int j = 0; j < MJ; j++)
          H[(size_t)row * (MJ * 64) + j * 64 + lane] = acc[r][j];
        if constexpr (FUSE) {
#pragma unroll
          for (int j = 0; j < MJ; j++) {
            float ps = wave_sum(acc[r][j] * atts[j]);
            float pd = wave_sum(acc[r][j] * attd[j]);
            if (lane == 0) {
              a_src[row * MJ + j] = ps;
              a_dst[row * MJ + j] = pd;
            }
          }
        }
      }
    }
  }
}

// ---------------- GCN aggregation: wave per node, lane = channel ----------------
__global__ __launch_bounds__(256) void k_gcn_agg(
    const float* __restrict__ h, const float* __restrict__ dinv,
    const int* __restrict__ rowstart, const int* __restrict__ colidx,
    const float* __restrict__ bias, float* __restrict__ out, int n) {
  int node = (blockIdx.x * blockDim.x + threadIdx.x) >> 6;
  int lane = threadIdx.x & 63;
  if (node >= n) return;
  int s0 = rowstart[node], s1 = rowstart[node + 1];
  float acc = 0.0f;
  for (int idx = s0; idx < s1; ++idx) {
    int s = colidx[idx];
    acc = fmaf(dinv[s], h[(size_t)s * 64 + lane], acc);
  }
  float r = fmaf(dinv[node], acc, bias[lane]);
  out[(size_t)node * 64 + lane] = fmaxf(r, 0.0f);
}

// ---------------- GAT aggregation: single fused softmax+aggregate pass ----------
// alpha = exp(e)/sum(exp(e)); max-shift cancels exactly and |e|<<1 here, so it
// is dropped. Per edge: 16B a_src gather + 4x coalesced 256B hg gathers.
__global__ __launch_bounds__(256) void k_gat_agg(
    const float* __restrict__ hg, const float* __restrict__ a_src,
    const float* __restrict__ a_dst, const int* __restrict__ rowstart,
    const int* __restrict__ colidx, const float* __restrict__ bias,
    float* __restrict__ out, int n) {
  int node = (blockIdx.x * blockDim.x + threadIdx.x) >> 6;
  int lane = threadIdx.x & 63;
  if (node >= n) return;
  const float4 adv = *(const float4*)&a_dst[node * 4];
  int s0 = rowstart[node], s1 = rowstart[node + 1];
  float acc0 = 0, acc1 = 0, acc2 = 0, acc3 = 0;
  float S0 = 0, S1 = 0, S2 = 0, S3 = 0;
  for (int idx = s0; idx < s1; ++idx) {
    int s = colidx[idx];
    const float4 as = *(const float4*)&a_src[s * 4];
    float e0 = as.x + adv.x; e0 = (e0 > 0.f) ? e0 : 0.2f * e0; float w0 = __expf(e0);
    float e1 = as.y + adv.y; e1 = (e1 > 0.f) ? e1 : 0.2f * e1; float w1 = __expf(e1);
    float e2 = as.z + adv.z; e2 = (e2 > 0.f) ? e2 : 0.2f * e2; float w2 = __expf(e2);
    float e3 = as.w + adv.w; e3 = (e3 > 0.f) ? e3 : 0.2f * e3; float w3 = __expf(e3);
    S0 += w0; S1 += w1; S2 += w2; S3 += w3;
    const float* hr = hg + (size_t)s * 256;
    acc0 = fmaf(w0, hr[lane], acc0);
    acc1 = fmaf(w1, hr[64 + lane], acc1);
    acc2 = fmaf(w2, hr[128 + lane], acc2);
    acc3 = fmaf(w3, hr[192 + lane], acc3);
  }
  float r = 0.25f * (acc0 / S0 + acc1 / S1 + acc2 / S2 + acc3 / S3) + bias[lane];
  out[(size_t)node * 64 + lane] = fmaxf(r, 0.0f);
}

// ---------------- pooling ----------------
__global__ void k_gstart(const int* __restrict__ batch, int* gs, int n, int B) {
  int g = blockIdx.x * blockDim.x + threadIdx.x;
  if (g > B) return;
  int lo = 0, hi = n;
  while (lo < hi) {
    int mid = (lo + hi) >> 1;
    if (batch[mid] < g) lo = mid + 1; else hi = mid;
  }
  gs[g] = lo;
}

__global__ __launch_bounds__(256) void k_pool(const float* __restrict__ x,
                                              const int* __restrict__ gs,
                                              float* __restrict__ gvec, int B) {
  int g = (blockIdx.x * blockDim.x + threadIdx.x) >> 6;
  int lane = threadIdx.x & 63;
  if (g >= B) return;
  int s0 = gs[g], s1 = gs[g + 1];
  float sum = 0.0f, mx = -INFINITY;
  for (int nd = s0; nd < s1; ++nd) {
    float v = x[(size_t)nd * 64 + lane];
    sum += v;
    mx = fmaxf(mx, v);
  }
  int cnt = s1 - s0;
  float mean = sum / fmaxf((float)cnt, 1.0f);
  float mp = (cnt > 0) ? mx : 0.0f;
  gvec[g * 64 + lane] = mean + mp;
}

// ---------------- MLP head ----------------
__global__ __launch_bounds__(256) void k_mlp(const float* __restrict__ gvec,
                                             const float* __restrict__ w1,
                                             const float* __restrict__ b1,
                                             const float* __restrict__ w2,
                                             const float* __restrict__ b2,
                                             float* __restrict__ out, int B) {
  int g = blockIdx.x * blockDim.x + threadIdx.x;
  if (g >= B) return;
  float gv[64];
#pragma unroll
  for (int i = 0; i < 64; i++) gv[i] = gvec[g * 64 + i];
  float o0 = b2[0], o1 = b2[1];
  for (int j = 0; j < 32; j++) {
    float a = b1[j];
#pragma unroll
    for (int i = 0; i < 64; i++) a = fmaf(gv[i], w1[i * 32 + j], a);
    a = fmaxf(a, 0.0f);
    o0 = fmaf(a, w2[j * 2 + 0], o0);
    o1 = fmaf(a, w2[j * 2 + 1], o1);
  }
  out[g * 2 + 0] = o0;
  out[g * 2 + 1] = o1;
}

// ---------------- launch ----------------
extern "C" void kernel_launch(void* const* d_in, const int* in_sizes, int n_in,
                              void* d_out, int out_size, void* d_ws, size_t ws_size,
                              hipStream_t stream) {
  const float* x     = (const float*)d_in[0];
  const int*   ei    = (const int*)d_in[1];
  const int*   batch = (const int*)d_in[2];
  const float* w0 = (const float*)d_in[3];  const float* b0 = (const float*)d_in[4];
  const float* w1 = (const float*)d_in[5];  const float* b1 = (const float*)d_in[6];
  const float* w2 = (const float*)d_in[7];  const float* b2 = (const float*)d_in[8];
  const float* gat_w = (const float*)d_in[9];
  const float* att_s = (const float*)d_in[10];
  const float* att_d = (const float*)d_in[11];
  const float* gat_b = (const float*)d_in[12];
  const float* l1w = (const float*)d_in[13]; const float* l1b = (const float*)d_in[14];
  const float* l2w = (const float*)d_in[15]; const float* l2b = (const float*)d_in[16];

  const int N = in_sizes[0] / 128;
  const int E = in_sizes[1] / 2;
  const int B = out_size / 2;

  char* ws = (char*)d_ws;
  size_t off = 0;
  auto alloc = [&](size_t bytes) -> void* {
    void* p = ws + off;
    off = (off + bytes + 255) & ~(size_t)255;
    return p;
  };
  int*   deg      = (int*)alloc((size_t)N * 4);
  int*   cursor   = (int*)alloc((size_t)N * 4);
  int*   rowstart = (int*)alloc((size_t)(N + 1) * 4);
  int*   colidx   = (int*)alloc((size_t)(E + N) * 4);
  float* dinv     = (float*)alloc((size_t)N * 4);
  float* hbuf     = (float*)alloc((size_t)N * 64 * 4);
  float* act      = (float*)alloc((size_t)N * 64 * 4);
  float* hg       = (float*)alloc((size_t)N * 256 * 4);
  float* a_src    = (float*)alloc((size_t)N * 4 * 4);
  float* a_dst    = (float*)alloc((size_t)N * 4 * 4);
  int*   gs       = (int*)alloc((size_t)(B + 1) * 4);
  float* gvec     = (float*)alloc((size_t)B * 64 * 4);
  (void)ws_size; (void)n_in;

  // CSR build
  k_initdeg<<<(N + 255) / 256, 256, 0, stream>>>(deg, N);
  k_count<<<(E + 255) / 256, 256, 0, stream>>>(ei + E, deg, E);
  k_scan<<<1, 1024, 0, stream>>>(deg, rowstart, cursor, N);
  k_dinv<<<(N + 255) / 256, 256, 0, stream>>>(deg, dinv, N);
  k_scatter<<<(E + N + 255) / 256, 256, 0, stream>>>(ei, ei + E, cursor, colidx, E, N);

  const int GB = 1280;  // grid-stride GEMM blocks (5/CU)
  // GCN layer 0
  k_gemm<128, 1, false><<<GB, 256, 0, stream>>>(x, w0, hbuf, N, nullptr, nullptr, nullptr, nullptr);
  k_gcn_agg<<<(N + 3) / 4, 256, 0, stream>>>(hbuf, dinv, rowstart, colidx, b0, act, N);
  // GCN layer 1
  k_gemm<64, 1, false><<<GB, 256, 0, stream>>>(act, w1, hbuf, N, nullptr, nullptr, nullptr, nullptr);
  k_gcn_agg<<<(N + 3) / 4, 256, 0, stream>>>(hbuf, dinv, rowstart, colidx, b1, act, N);
  // GCN layer 2
  k_gemm<64, 1, false><<<GB, 256, 0, stream>>>(act, w2, hbuf, N, nullptr, nullptr, nullptr, nullptr);
  k_gcn_agg<<<(N + 3) / 4, 256, 0, stream>>>(hbuf, dinv, rowstart, colidx, b2, act, N);
  // GAT
  k_gemm<64, 4, true><<<GB, 256, 0, stream>>>(act, gat_w, hg, N, att_s, att_d, a_src, a_dst);
  k_gat_agg<<<(N + 3) / 4, 256, 0, stream>>>(hg, a_src, a_dst, rowstart, colidx, gat_b, act, N);
  // pooling + head
  k_gstart<<<(B + 1 + 255) / 256, 256, 0, stream>>>(batch, gs, N, B);
  k_pool<<<(B + 3) / 4, 256, 0, stream>>>(act, gs, gvec, B);
  k_mlp<<<(B + 255) / 256, 256, 0, stream>>>(gvec, l1w, l1b, l2w, l2b, (float*)d_out, B);
}